// Round 3
// baseline (61.551 us; speedup 1.0000x reference)
//
#include <hip/hip_runtime.h>

// 16 x 8 x 512 x 512 fp32; 2x2 grey opening + MSE (scalar out)
#define IMG_H 512
#define IMG_W 512
#define NIMG 128
#define CHUNK 16
#define NCHUNK (IMG_H / CHUNK)          // 32
#define THREADS 256
#define WPB (THREADS / 64)              // 4 waves / block
#define NBLOCKS (NIMG * NCHUNK / WPB)   // 1024 -> 4 waves/SIMD

__global__ __launch_bounds__(THREADS, 4)
void opening_mse_kernel(const float* __restrict__ X, float* __restrict__ out) {
    const int lane = threadIdx.x & 63;
    const int gw   = blockIdx.x * WPB + (threadIdx.x >> 6);
    const int n     = gw >> 5;               // image 0..127
    const int chunk = gw & (NCHUNK - 1);     // 0..31
    const int s = chunk * CHUNK;
    const int e = s + CHUNK;                 // output rows [s, e)
    const float* __restrict__ img = X + (size_t)n * (IMG_H * IMG_W);
    const int cb = lane << 3;                // 8 cols/lane; wave spans 512 cols

    auto ld = [&](int r, float4& a, float4& b) {
        const float* __restrict__ p = img + (size_t)r * IMG_W + cb;
        a = *reinterpret_cast<const float4*>(p);
        b = *reinterpret_cast<const float4*>(p + 4);
    };

    // h[k] = min(x[c-1], x[c]) for c = cb+k, k=0..8; h[8] is the dilation's
    // right-neighbor column (lane 63: h[8]=h[7] == reflect clamp at col 511).
    auto mkh = [&](const float4& a, const float4& b, float (&h)[9]) {
        float xl = __shfl_up(b.w, 1, 64);
        if (lane == 0) xl = a.x;
        float xr = __shfl_down(a.x, 1, 64);
        h[0] = fminf(xl, a.x);
        h[1] = fminf(a.x, a.y);
        h[2] = fminf(a.y, a.z);
        h[3] = fminf(a.z, a.w);
        h[4] = fminf(a.w, b.x);
        h[5] = fminf(b.x, b.y);
        h[6] = fminf(b.y, b.z);
        h[7] = fminf(b.z, b.w);
        h[8] = (lane == 63) ? h[7] : fminf(b.w, xr);
    };

    float hprev[9], hd[8];
    float4 xa, xb;   // x of the row whose opened value we emit next (row a-1)

    {   // prime: h(row s-1 clamped), h(row s), hd[s]
        float4 ta, tb;
        ld(s > 0 ? s - 1 : 0, ta, tb);
        mkh(ta, tb, hprev);
        ld(s, xa, xb);
        float hcur[9], E[9];
        mkh(xa, xb, hcur);
        #pragma unroll
        for (int k = 0; k < 9; ++k) E[k] = fminf(hprev[k], hcur[k]);
        #pragma unroll
        for (int k = 0; k < 8; ++k) hd[k] = fmaxf(E[k], E[k + 1]);
        #pragma unroll
        for (int k = 0; k < 9; ++k) hprev[k] = hcur[k];
    }

    // depth-4 register ring of row prefetches (s+1..s+4 always < IMG_H: s<=496)
    float4 p1a, p1b, p2a, p2b, p3a, p3b, p4a, p4b;
    ld(s + 1, p1a, p1b);
    ld(s + 2, p2a, p2b);
    ld(s + 3, p3a, p3b);
    ld(s + 4, p4a, p4b);

    float acc = 0.0f;
    #pragma unroll 4
    for (int a = s + 1; a <= e; ++a) {
        float4 ca = p1a, cbv = p1b;
        p1a = p2a; p1b = p2b;
        p2a = p3a; p2b = p3b;
        p3a = p4a; p3b = p4b;
        int rn = a + 4;                       // branch-free clamp; overshoot rows
        rn = rn < IMG_H ? rn : IMG_H - 1;     // are L2-shared with next chunk
        ld(rn, p4a, p4b);

        float hdc[8];
        if (a < IMG_H) {
            float hcur[9], E[9];
            mkh(ca, cbv, hcur);
            #pragma unroll
            for (int k = 0; k < 9; ++k) E[k] = fminf(hprev[k], hcur[k]);
            #pragma unroll
            for (int k = 0; k < 8; ++k) hdc[k] = fmaxf(E[k], E[k + 1]);
            #pragma unroll
            for (int k = 0; k < 9; ++k) hprev[k] = hcur[k];
        } else {
            #pragma unroll
            for (int k = 0; k < 8; ++k) hdc[k] = hd[k];   // hd[H] := hd[H-1]
        }

        // opened row a-1 = max(hd[a-1], hd[a]); accumulate squared error vs x
        float d;
        d = xa.x - fmaxf(hd[0], hdc[0]); acc = fmaf(d, d, acc);
        d = xa.y - fmaxf(hd[1], hdc[1]); acc = fmaf(d, d, acc);
        d = xa.z - fmaxf(hd[2], hdc[2]); acc = fmaf(d, d, acc);
        d = xa.w - fmaxf(hd[3], hdc[3]); acc = fmaf(d, d, acc);
        d = xb.x - fmaxf(hd[4], hdc[4]); acc = fmaf(d, d, acc);
        d = xb.y - fmaxf(hd[5], hdc[5]); acc = fmaf(d, d, acc);
        d = xb.z - fmaxf(hd[6], hdc[6]); acc = fmaf(d, d, acc);
        d = xb.w - fmaxf(hd[7], hdc[7]); acc = fmaf(d, d, acc);

        #pragma unroll
        for (int k = 0; k < 8; ++k) hd[k] = hdc[k];
        xa = ca; xb = cbv;
    }

    // wave shuffle reduce -> LDS across 4 waves -> one atomic per block
    #pragma unroll
    for (int off = 32; off > 0; off >>= 1)
        acc += __shfl_down(acc, off, 64);

    __shared__ float wsum[WPB];
    const int wid = threadIdx.x >> 6;
    if (lane == 0) wsum[wid] = acc;
    __syncthreads();
    if (threadIdx.x == 0) {
        float sblk = wsum[0] + wsum[1] + wsum[2] + wsum[3];
        atomicAdd(out, sblk * (1.0f / 33554432.0f));   // / 2^25 -> mean
    }
}

extern "C" void kernel_launch(void* const* d_in, const int* in_sizes, int n_in,
                              void* d_out, int out_size, void* d_ws, size_t ws_size,
                              hipStream_t stream) {
    const float* X = (const float*)d_in[0];
    float* out = (float*)d_out;
    hipMemsetAsync(out, 0, sizeof(float), stream);
    opening_mse_kernel<<<NBLOCKS, THREADS, 0, stream>>>(X, out);
}

// Round 4
// 40.479 us; speedup vs baseline: 1.5206x; 1.5206x over previous
//
#include <hip/hip_runtime.h>

// 16 x 8 x 512 x 512 fp32; 2x2 grey opening + MSE (scalar out)
#define IMG_H 512
#define IMG_W 512
#define NIMG 128
#define CHUNK 16
#define NCHUNK (IMG_H / CHUNK)          // 32
#define THREADS 256
#define WPB (THREADS / 64)              // 4 waves / block
#define NBLOCKS (NIMG * NCHUNK / WPB)   // 1024 -> 4 waves/SIMD at <=128 VGPR

__global__ __launch_bounds__(THREADS, 4)
void opening_mse_kernel(const float* __restrict__ X, float* __restrict__ out) {
    const int lane = threadIdx.x & 63;
    const int gw   = blockIdx.x * WPB + (threadIdx.x >> 6);
    const int n     = gw >> 5;               // image 0..127
    const int chunk = gw & (NCHUNK - 1);     // 0..31
    const int s = chunk * CHUNK;
    const int e = s + CHUNK;                 // output rows [s, e)
    const float* __restrict__ img = X + (size_t)n * (IMG_H * IMG_W);
    const int cb = lane << 3;                // 8 cols/lane; wave spans 512 cols

    auto ld = [&](int r, float4& a, float4& b) {
        const float* __restrict__ p = img + (size_t)r * IMG_W + cb;
        a = *reinterpret_cast<const float4*>(p);
        b = *reinterpret_cast<const float4*>(p + 4);
    };

    // h[k] = min(x[c-1], x[c]) for c = cb+k, k=0..8; h[8] is the dilation's
    // right-neighbor column (lane 63: h[8]=h[7] == reflect clamp at col 511).
    auto mkh = [&](const float4& a, const float4& b, float (&h)[9]) {
        float xl = __shfl_up(b.w, 1, 64);
        if (lane == 0) xl = a.x;
        float xr = __shfl_down(a.x, 1, 64);
        h[0] = fminf(xl, a.x);
        h[1] = fminf(a.x, a.y);
        h[2] = fminf(a.y, a.z);
        h[3] = fminf(a.z, a.w);
        h[4] = fminf(a.w, b.x);
        h[5] = fminf(b.x, b.y);
        h[6] = fminf(b.y, b.z);
        h[7] = fminf(b.z, b.w);
        h[8] = (lane == 63) ? h[7] : fminf(b.w, xr);
    };

    float hprev[9], hd[8];
    float4 xa, xb;   // x of the row whose opened value we emit next (row a-1)

    {   // prime: h(row s-1 clamped), h(row s), hd[s]
        float4 ta, tb;
        ld(s > 0 ? s - 1 : 0, ta, tb);
        mkh(ta, tb, hprev);
        ld(s, xa, xb);
        float hcur[9], E[9];
        mkh(xa, xb, hcur);
        #pragma unroll
        for (int k = 0; k < 9; ++k) E[k] = fminf(hprev[k], hcur[k]);
        #pragma unroll
        for (int k = 0; k < 8; ++k) hd[k] = fmaxf(E[k], E[k + 1]);
        #pragma unroll
        for (int k = 0; k < 9; ++k) hprev[k] = hcur[k];
    }

    // depth-2 register ring of row prefetches (s+1, s+2 always < IMG_H: s<=496)
    float4 p1a, p1b, p2a, p2b;
    ld(s + 1, p1a, p1b);
    ld(s + 2, p2a, p2b);

    float acc = 0.0f;
    #pragma unroll 2
    for (int a = s + 1; a <= e; ++a) {
        float4 ca = p1a, cbv = p1b;
        p1a = p2a; p1b = p2b;
        int rn = a + 2;                       // branch-free clamp; overshoot rows
        rn = rn < IMG_H ? rn : IMG_H - 1;     // are L2-shared with next chunk
        ld(rn, p2a, p2b);

        float hdc[8];
        if (a < IMG_H) {
            float hcur[9], E[9];
            mkh(ca, cbv, hcur);
            #pragma unroll
            for (int k = 0; k < 9; ++k) E[k] = fminf(hprev[k], hcur[k]);
            #pragma unroll
            for (int k = 0; k < 8; ++k) hdc[k] = fmaxf(E[k], E[k + 1]);
            #pragma unroll
            for (int k = 0; k < 9; ++k) hprev[k] = hcur[k];
        } else {
            #pragma unroll
            for (int k = 0; k < 8; ++k) hdc[k] = hd[k];   // hd[H] := hd[H-1]
        }

        // opened row a-1 = max(hd[a-1], hd[a]); accumulate squared error vs x
        float d;
        d = xa.x - fmaxf(hd[0], hdc[0]); acc = fmaf(d, d, acc);
        d = xa.y - fmaxf(hd[1], hdc[1]); acc = fmaf(d, d, acc);
        d = xa.z - fmaxf(hd[2], hdc[2]); acc = fmaf(d, d, acc);
        d = xa.w - fmaxf(hd[3], hdc[3]); acc = fmaf(d, d, acc);
        d = xb.x - fmaxf(hd[4], hdc[4]); acc = fmaf(d, d, acc);
        d = xb.y - fmaxf(hd[5], hdc[5]); acc = fmaf(d, d, acc);
        d = xb.z - fmaxf(hd[6], hdc[6]); acc = fmaf(d, d, acc);
        d = xb.w - fmaxf(hd[7], hdc[7]); acc = fmaf(d, d, acc);

        #pragma unroll
        for (int k = 0; k < 8; ++k) hd[k] = hdc[k];
        xa = ca; xb = cbv;
    }

    // wave shuffle reduce -> LDS across 4 waves -> one atomic per block
    #pragma unroll
    for (int off = 32; off > 0; off >>= 1)
        acc += __shfl_down(acc, off, 64);

    __shared__ float wsum[WPB];
    const int wid = threadIdx.x >> 6;
    if (lane == 0) wsum[wid] = acc;
    __syncthreads();
    if (threadIdx.x == 0) {
        float sblk = wsum[0] + wsum[1] + wsum[2] + wsum[3];
        atomicAdd(out, sblk * (1.0f / 33554432.0f));   // / 2^25 -> mean
    }
}

extern "C" void kernel_launch(void* const* d_in, const int* in_sizes, int n_in,
                              void* d_out, int out_size, void* d_ws, size_t ws_size,
                              hipStream_t stream) {
    const float* X = (const float*)d_in[0];
    float* out = (float*)d_out;
    hipMemsetAsync(out, 0, sizeof(float), stream);
    opening_mse_kernel<<<NBLOCKS, THREADS, 0, stream>>>(X, out);
}